// Round 5
// baseline (448.812 us; speedup 1.0000x reference)
//
#include <hip/hip_runtime.h>

// SAGE mean-aggregation + linear:  out = (segment_sum(x[col], row) / (deg+eps)) @ W^T + b
// N=40000 nodes, E=640000 edges, F_IN=F_OUT=128, fp32.
//
// Pipeline (all on `stream`, ws ~2.9 MB):
//   memset  : zero deg[40000]                  (hipMemsetAsync — capture-safe)
//   k_count : deg[row[e]]++                    (640K int atomics)
//   k_scan  : exclusive prefix sum -> cursor   (single 1024-thread block)
//   k_fill  : csr[cursor[row[e]]++] = col[e]   (640K int atomics)
//   k_agg   : per-node pull: mean row -> d_out (wave/node, float4, half-wave/edge)
//   k_gemm  : in-place d_out = d_out @ W^T + b (thread/node, A in VGPRs, W via s_load)
//
// R4 post-mortem: k_gemm 80us, VALUBusy 45% — LDS pipe oversubscribed ~4x by
// A-operand b128 broadcasts (4 SIMDs share 1 LDS pipe; 142 LDS-cyc vs 128
// SIMD-cyc per wave per k4). R5: no-LDS gemm — A row in registers (1 node per
// thread), W streamed on the SCALAR pipe (uniform loads -> s_load; v_fma takes
// 1 SGPR operand). Predicted k_gemm ~14-20us, issue-bound.

constexpr int NN = 40000;
constexpr int NE = 640000;
constexpr float EPS = 1e-6f;

__global__ __launch_bounds__(256) void k_count(const int* __restrict__ row,
                                               int* __restrict__ deg) {
  int e = blockIdx.x * 256 + threadIdx.x;
  if (e < NE) atomicAdd(&deg[row[e]], 1);
}

// single-block exclusive scan of deg[0..NN) into cursor[0..NN)
__global__ __launch_bounds__(1024) void k_scan(const int* __restrict__ deg,
                                               int* __restrict__ cursor) {
  __shared__ int s[1024];
  const int t = threadIdx.x;
  constexpr int CH = 40;                 // 1024*40 = 40960 >= 40000
  const int base = t * CH;
  int sum = 0;
  for (int i = 0; i < CH; ++i) {
    int idx = base + i;
    if (idx < NN) sum += deg[idx];
  }
  s[t] = sum;
  __syncthreads();
  for (int off = 1; off < 1024; off <<= 1) {
    int v = (t >= off) ? s[t - off] : 0;
    __syncthreads();
    s[t] += v;
    __syncthreads();
  }
  int run = (t == 0) ? 0 : s[t - 1];
  for (int i = 0; i < CH; ++i) {
    int idx = base + i;
    if (idx < NN) { cursor[idx] = run; run += deg[idx]; }
  }
}

__global__ __launch_bounds__(256) void k_fill(const int* __restrict__ row,
                                              const int* __restrict__ col,
                                              int* __restrict__ cursor,
                                              int* __restrict__ csr) {
  int e = blockIdx.x * 256 + threadIdx.x;
  if (e < NE) {
    int pos = atomicAdd(&cursor[row[e]], 1);
    csr[pos] = col[e];
  }
}

// One wave per destination node. Half-wave per edge, float4 row loads
// (1 KiB per wave VMEM op), 4 gathers in flight per half-wave.
__global__ __launch_bounds__(256) void k_agg(const float4* __restrict__ x4,
                                             const int* __restrict__ csr,
                                             const int* __restrict__ deg,
                                             const int* __restrict__ cursor,
                                             float4* __restrict__ out4) {
  const int wid  = threadIdx.x >> 6;
  const int lane = threadIdx.x & 63;
  const int half = lane >> 5;      // which edge of the pair
  const int fl   = lane & 31;      // float4 slot within the 128-float row
  const int n = blockIdx.x * 4 + wid;        // grid = 10000 -> exact
  const int end = cursor[n];                 // after k_fill: start + deg
  const int d = deg[n];
  const int start = end - d;
  float ax = 0.f, ay = 0.f, az = 0.f, aw = 0.f;
  for (int j = 0; j < d; j += 8) {
#pragma unroll
    for (int u = 0; u < 4; ++u) {
      int jj = j + 2 * u + half;
      if (jj < d) {
        int c = csr[start + jj];
        float4 v = x4[(size_t)c * 32 + fl];
        ax += v.x; ay += v.y; az += v.z; aw += v.w;
      }
    }
  }
  ax += __shfl_xor(ax, 32);
  ay += __shfl_xor(ay, 32);
  az += __shfl_xor(az, 32);
  aw += __shfl_xor(aw, 32);
  const float sc = 1.0f / ((float)d + EPS);
  if (half == 0) {
    float4 o;
    o.x = ax * sc; o.y = ay * sc; o.z = az * sc; o.w = aw * sc;
    out4[(size_t)n * 32 + fl] = o;
  }
}

// In-place: out[n][:] = mean_row(out[n]) @ W^T + b.  One node per THREAD.
// A row (128 floats) lives in VGPRs (all indices compile-time -> SROA).
// W/b accesses are wave-uniform on __restrict__ const args -> scalar loads on
// the SMEM pipe; v_fma_f32 reads the W value as its one SGPR operand.
// No LDS, no barriers. 4 independent acc chains per f-group -> issue-bound.
__global__ __launch_bounds__(256) void k_gemm(const float* __restrict__ W,
                                              const float* __restrict__ b,
                                              float* __restrict__ out) {
  const int n = blockIdx.x * 256 + threadIdx.x;
  if (n >= NN) return;
  float* orow = out + (size_t)n * 128;
  float4 A[32];
  {
    const float4* a4 = (const float4*)orow;
#pragma unroll
    for (int i = 0; i < 32; ++i) A[i] = a4[i];
  }
  for (int fg = 0; fg < 32; ++fg) {          // f-group = 4 output features
    const float* W0 = W + (size_t)(4 * fg + 0) * 128;
    const float* W1 = W + (size_t)(4 * fg + 1) * 128;
    const float* W2 = W + (size_t)(4 * fg + 2) * 128;
    const float* W3 = W + (size_t)(4 * fg + 3) * 128;
    float s0 = 0.f, s1 = 0.f, s2 = 0.f, s3 = 0.f;
#pragma unroll
    for (int q = 0; q < 32; ++q) {           // k = 4q..4q+3, fully static
      const float4 av = A[q];
      s0 = fmaf(av.x, W0[4 * q + 0], s0);
      s0 = fmaf(av.y, W0[4 * q + 1], s0);
      s0 = fmaf(av.z, W0[4 * q + 2], s0);
      s0 = fmaf(av.w, W0[4 * q + 3], s0);
      s1 = fmaf(av.x, W1[4 * q + 0], s1);
      s1 = fmaf(av.y, W1[4 * q + 1], s1);
      s1 = fmaf(av.z, W1[4 * q + 2], s1);
      s1 = fmaf(av.w, W1[4 * q + 3], s1);
      s2 = fmaf(av.x, W2[4 * q + 0], s2);
      s2 = fmaf(av.y, W2[4 * q + 1], s2);
      s2 = fmaf(av.z, W2[4 * q + 2], s2);
      s2 = fmaf(av.w, W2[4 * q + 3], s2);
      s3 = fmaf(av.x, W3[4 * q + 0], s3);
      s3 = fmaf(av.y, W3[4 * q + 1], s3);
      s3 = fmaf(av.z, W3[4 * q + 2], s3);
      s3 = fmaf(av.w, W3[4 * q + 3], s3);
    }
    float4 o;
    o.x = s0 + b[4 * fg + 0];
    o.y = s1 + b[4 * fg + 1];
    o.z = s2 + b[4 * fg + 2];
    o.w = s3 + b[4 * fg + 3];
    *(float4*)&orow[4 * fg] = o;             // A already in regs: in-place safe
  }
}

extern "C" void kernel_launch(void* const* d_in, const int* in_sizes, int n_in,
                              void* d_out, int out_size, void* d_ws, size_t ws_size,
                              hipStream_t stream) {
  const float* x   = (const float*)d_in[0];
  const int*   row = (const int*)d_in[1];
  const int*   col = (const int*)d_in[2];
  const float* W   = (const float*)d_in[3];
  const float* b   = (const float*)d_in[4];
  float* out = (float*)d_out;

  char* ws = (char*)d_ws;
  int* deg    = (int*)(ws + 0);        // 160000 B
  int* cursor = (int*)(ws + 163840);   // 160000 B
  int* csr    = (int*)(ws + 327680);   // 2560000 B  -> total ~2.89 MB

  hipMemsetAsync(deg, 0, NN * sizeof(int), stream);
  k_count<<<NE / 256,         256, 0, stream>>>(row, deg);
  k_scan <<<1,               1024, 0, stream>>>(deg, cursor);
  k_fill <<<NE / 256,         256, 0, stream>>>(row, col, cursor, csr);
  k_agg  <<<NN / 4,           256, 0, stream>>>((const float4*)x, csr, deg, cursor,
                                                (float4*)out);
  k_gemm <<<(NN + 255) / 256, 256, 0, stream>>>(W, b, out);
}

// Round 7
// 284.744 us; speedup vs baseline: 1.5762x; 1.5762x over previous
//
#include <hip/hip_runtime.h>

// SAGE mean-aggregation + linear:  out = (segment_sum(x[col], row) / (deg+eps)) @ W^T + b
// N=40000, E=640000, F_IN=F_OUT=128, fp32 in/out.
//
// R5 post-mortem: per-thread-node gemm collapsed occupancy (157 blocks, VALUBusy 7%).
// R6: (1) GEMM via MFMA on exact bf16 hi/lo split (3 products; err ~1e-4 << absmax
//     0.0039 which is reference-quantization-dominated — bit-identical across 5
//     rounds). k_agg packs mean as (hi<<16)|lo into d_out; k_gemm unpacks, uses
//     m91-verified 16x16x32 bf16 fragments (B^T-GEMM form == mean @ W.T).
//     (2) k_agg: 8 gathers in flight per half-wave (covers avg deg 16 in one
//     latency round) to push the 327MB gather toward BW-bound.
// R7: resubmit (R6 never ran — GPU acquisition timeout). Source re-audited:
//     alias-safety, fragment mapping, packing addressing all verified.

typedef short bf16x8 __attribute__((ext_vector_type(8)));
typedef float f32x4  __attribute__((ext_vector_type(4)));
typedef unsigned short ushort_t;

constexpr int NN = 40000;
constexpr int NE = 640000;
constexpr float EPS = 1e-6f;

__global__ __launch_bounds__(256) void k_count(const int* __restrict__ row,
                                               int* __restrict__ deg) {
  int e = blockIdx.x * 256 + threadIdx.x;
  if (e < NE) atomicAdd(&deg[row[e]], 1);
}

// single-block exclusive scan of deg[0..NN) into cursor[0..NN)
__global__ __launch_bounds__(1024) void k_scan(const int* __restrict__ deg,
                                               int* __restrict__ cursor) {
  __shared__ int s[1024];
  const int t = threadIdx.x;
  constexpr int CH = 40;                 // 1024*40 = 40960 >= 40000
  const int base = t * CH;
  int sum = 0;
  for (int i = 0; i < CH; ++i) {
    int idx = base + i;
    if (idx < NN) sum += deg[idx];
  }
  s[t] = sum;
  __syncthreads();
  for (int off = 1; off < 1024; off <<= 1) {
    int v = (t >= off) ? s[t - off] : 0;
    __syncthreads();
    s[t] += v;
    __syncthreads();
  }
  int run = (t == 0) ? 0 : s[t - 1];
  for (int i = 0; i < CH; ++i) {
    int idx = base + i;
    if (idx < NN) { cursor[idx] = run; run += deg[idx]; }
  }
}

__global__ __launch_bounds__(256) void k_fill(const int* __restrict__ row,
                                              const int* __restrict__ col,
                                              int* __restrict__ cursor,
                                              int* __restrict__ csr) {
  int e = blockIdx.x * 256 + threadIdx.x;
  if (e < NE) {
    int pos = atomicAdd(&cursor[row[e]], 1);
    csr[pos] = col[e];
  }
}

// Split W (fp32 [128][128]) into bf16 hi/lo arrays (RNE both stages).
__global__ __launch_bounds__(256) void k_wsplit(const float* __restrict__ W,
                                                ushort_t* __restrict__ Wh,
                                                ushort_t* __restrict__ Wl) {
  int i = blockIdx.x * 256 + threadIdx.x;        // 16384 elems, grid 64
  float w = W[i];
  unsigned fb = __float_as_uint(w);
  unsigned hb = (fb + 0x7fffu + ((fb >> 16) & 1u)) >> 16;
  float hf = __uint_as_float(hb << 16);
  float r = w - hf;
  unsigned rb = __float_as_uint(r);
  unsigned lb = (rb + 0x7fffu + ((rb >> 16) & 1u)) >> 16;
  Wh[i] = (ushort_t)hb;
  Wl[i] = (ushort_t)lb;
}

__device__ inline unsigned pack_split(float m) {
  unsigned fb = __float_as_uint(m);
  unsigned hb = (fb + 0x7fffu + ((fb >> 16) & 1u)) >> 16;   // RNE bf16
  float hf = __uint_as_float(hb << 16);
  float r = m - hf;
  unsigned rb = __float_as_uint(r);
  unsigned lb = (rb + 0x7fffu + ((rb >> 16) & 1u)) >> 16;   // RNE bf16 of residual
  return (hb << 16) | (lb & 0xffffu);
}

// One wave per destination node. Half-wave per edge, float4 row loads (each
// instruction covers 2 edges x 512B = 1KiB). 8 gathers in flight per half-wave
// -> avg degree 16 fully in flight in one latency round.
// Writes the mean row PACKED as (bf16_hi<<16)|bf16_lo into d_out (same 4B/elem).
__global__ __launch_bounds__(256) void k_agg(const float4* __restrict__ x4,
                                             const int* __restrict__ csr,
                                             const int* __restrict__ deg,
                                             const int* __restrict__ cursor,
                                             uint4* __restrict__ outp) {
  const int wid  = threadIdx.x >> 6;
  const int lane = threadIdx.x & 63;
  const int half = lane >> 5;      // which edge of the pair
  const int fl   = lane & 31;      // float4 slot within the 128-float row
  const int n = blockIdx.x * 4 + wid;        // grid = 10000 -> exact
  const int end = cursor[n];                 // after k_fill: start + deg
  const int d = deg[n];
  const int start = end - d;
  float ax = 0.f, ay = 0.f, az = 0.f, aw = 0.f;
  for (int j = 0; j < d; j += 16) {
#pragma unroll
    for (int u = 0; u < 8; ++u) {
      int jj = j + 2 * u + half;
      if (jj < d) {
        int c = csr[start + jj];
        float4 v = x4[(size_t)c * 32 + fl];
        ax += v.x; ay += v.y; az += v.z; aw += v.w;
      }
    }
  }
  ax += __shfl_xor(ax, 32);
  ay += __shfl_xor(ay, 32);
  az += __shfl_xor(az, 32);
  aw += __shfl_xor(aw, 32);
  const float sc = 1.0f / ((float)d + EPS);
  if (half == 0) {
    uint4 o;
    o.x = pack_split(ax * sc);
    o.y = pack_split(ay * sc);
    o.z = pack_split(az * sc);
    o.w = pack_split(aw * sc);
    outp[(size_t)n * 32 + fl] = o;
  }
}

#define MFMA16(a, b, c) __builtin_amdgcn_mfma_f32_16x16x32_bf16((a), (b), (c), 0, 0, 0)

// In-place: d_out currently holds packed hi/lo mean rows; overwrite with fp32
// out = mean @ W^T + b via MFMA.  One wave per 16-row M-tile (2500 tiles, 625
// blocks). Fragment pattern (m91-verified B^T GEMM): lane l reads
// A[row = l&15][k = (l>>4)*8 + j] and B[f = ftile*16 + (l&15)][same k]; C/D:
// col = lane&15, row = (lane>>4)*4 + reg. 3 products: AhBh + AhBl + AlBh
// (AlBl ~1e-5, dropped). No LDS, no barriers; all A reads precede stores.
// packed/out alias intentionally -> NOT __restrict__.
__global__ __launch_bounds__(256) void k_gemm(const unsigned* packed,
                                              const ushort_t* __restrict__ Wh,
                                              const ushort_t* __restrict__ Wl,
                                              const float* __restrict__ bias,
                                              float* out) {
  const int wid  = threadIdx.x >> 6;
  const int lane = threadIdx.x & 63;
  const int mt = blockIdx.x * 4 + wid;       // M-tile; 625*4 = 2500 -> exact
  const int r  = lane & 15;
  const int kg = lane >> 4;                  // 0..3
  const int arow = mt * 16 + r;
  f32x4 acc[8];
#pragma unroll
  for (int t = 0; t < 8; ++t) acc[t] = (f32x4){0.f, 0.f, 0.f, 0.f};
#pragma unroll
  for (int s = 0; s < 4; ++s) {              // k-step: k = s*32 + kg*8 .. +7
    const unsigned* ap = packed + (size_t)arow * 128 + s * 32 + kg * 8;
    const uint4 u0 = *(const uint4*)ap;
    const uint4 u1 = *(const uint4*)(ap + 4);
    bf16x8 Ah, Al;
    Ah[0] = (short)(u0.x >> 16); Al[0] = (short)u0.x;
    Ah[1] = (short)(u0.y >> 16); Al[1] = (short)u0.y;
    Ah[2] = (short)(u0.z >> 16); Al[2] = (short)u0.z;
    Ah[3] = (short)(u0.w >> 16); Al[3] = (short)u0.w;
    Ah[4] = (short)(u1.x >> 16); Al[4] = (short)u1.x;
    Ah[5] = (short)(u1.y >> 16); Al[5] = (short)u1.y;
    Ah[6] = (short)(u1.z >> 16); Al[6] = (short)u1.z;
    Ah[7] = (short)(u1.w >> 16); Al[7] = (short)u1.w;
#pragma unroll
    for (int t = 0; t < 8; ++t) {
      const size_t wo = (size_t)(t * 16 + r) * 128 + s * 32 + kg * 8;
      const bf16x8 Bh = *(const bf16x8*)(Wh + wo);
      const bf16x8 Bl = *(const bf16x8*)(Wl + wo);
      acc[t] = MFMA16(Ah, Bh, acc[t]);
      acc[t] = MFMA16(Ah, Bl, acc[t]);
      acc[t] = MFMA16(Al, Bh, acc[t]);
    }
  }
#pragma unroll
  for (int t = 0; t < 8; ++t) {
    const int f = t * 16 + r;                // C/D col = lane&15
    const float bf = bias[f];
#pragma unroll
    for (int j = 0; j < 4; ++j) {            // C/D row = kg*4 + j
      const int orow = mt * 16 + kg * 4 + j;
      out[(size_t)orow * 128 + f] = acc[t][j] + bf;
    }
  }
}

extern "C" void kernel_launch(void* const* d_in, const int* in_sizes, int n_in,
                              void* d_out, int out_size, void* d_ws, size_t ws_size,
                              hipStream_t stream) {
  const float* x   = (const float*)d_in[0];
  const int*   row = (const int*)d_in[1];
  const int*   col = (const int*)d_in[2];
  const float* W   = (const float*)d_in[3];
  const float* b   = (const float*)d_in[4];
  float* out = (float*)d_out;

  char* ws = (char*)d_ws;
  int*      deg    = (int*)(ws + 0);         // 160000 B
  int*      cursor = (int*)(ws + 163840);    // 160000 B
  int*      csr    = (int*)(ws + 327680);    // 2560000 B
  ushort_t* Wh     = (ushort_t*)(ws + 2887680);  // 32768 B
  ushort_t* Wl     = (ushort_t*)(ws + 2920448);  // 32768 B -> total ~2.95 MB

  hipMemsetAsync(deg, 0, NN * sizeof(int), stream);
  k_wsplit<<<64,       256, 0, stream>>>(W, Wh, Wl);
  k_count <<<NE / 256, 256, 0, stream>>>(row, deg);
  k_scan  <<<1,       1024, 0, stream>>>(deg, cursor);
  k_fill  <<<NE / 256, 256, 0, stream>>>(row, col, cursor, csr);
  k_agg   <<<NN / 4,   256, 0, stream>>>((const float4*)x, csr, deg, cursor,
                                         (uint4*)out);
  k_gemm  <<<NN / 64,  256, 0, stream>>>((const unsigned*)out, Wh, Wl, b, out);
}

// Round 8
// 218.485 us; speedup vs baseline: 2.0542x; 1.3033x over previous
//
#include <hip/hip_runtime.h>

// SAGE mean-aggregation + linear:  out = (segment_sum(x[col], row) / (deg+eps)) @ W^T + b
// N=40000, E=640000, F_IN=F_OUT=128, fp32 in/out.
//
// R7 post-mortem: k_scan (single 1024-thread block) = top dispatch, 76.9us,
// occupancy 0.15% — pure single-CU latency serialization (320KB of traffic!).
// R8: hierarchical scan (scanA: 157-block LDS block-scan + block sums;
// scanB: 1-block scan of 157 sums; scanC: add offsets). Everything else
// unchanged (MFMA gemm + packed hi/lo mean proven in R7: absmax 0.00390625).

typedef short bf16x8 __attribute__((ext_vector_type(8)));
typedef float f32x4  __attribute__((ext_vector_type(4)));
typedef unsigned short ushort_t;

constexpr int NN = 40000;
constexpr int NE = 640000;
constexpr int NB = (NN + 255) / 256;   // 157 scan blocks
constexpr float EPS = 1e-6f;

__global__ __launch_bounds__(256) void k_count(const int* __restrict__ row,
                                               int* __restrict__ deg) {
  int e = blockIdx.x * 256 + threadIdx.x;
  if (e < NE) atomicAdd(&deg[row[e]], 1);
}

// --- hierarchical exclusive scan of deg -> cursor ---------------------------
__global__ __launch_bounds__(256) void k_scanA(const int* __restrict__ deg,
                                               int* __restrict__ cursor,
                                               int* __restrict__ bsum) {
  __shared__ int s[256];
  const int t = threadIdx.x;
  const int i = blockIdx.x * 256 + t;
  const int v = (i < NN) ? deg[i] : 0;
  s[t] = v;
  __syncthreads();
  for (int off = 1; off < 256; off <<= 1) {
    int u = (t >= off) ? s[t - off] : 0;
    __syncthreads();
    s[t] += u;
    __syncthreads();
  }
  if (i < NN) cursor[i] = s[t] - v;          // exclusive within block
  if (t == 255) bsum[blockIdx.x] = s[255];
}

__global__ __launch_bounds__(256) void k_scanB(const int* __restrict__ bsum,
                                               int* __restrict__ boff) {
  __shared__ int s[256];
  const int t = threadIdx.x;
  const int v = (t < NB) ? bsum[t] : 0;
  s[t] = v;
  __syncthreads();
  for (int off = 1; off < 256; off <<= 1) {
    int u = (t >= off) ? s[t - off] : 0;
    __syncthreads();
    s[t] += u;
    __syncthreads();
  }
  if (t < NB) boff[t] = s[t] - v;            // exclusive block offsets
}

__global__ __launch_bounds__(256) void k_scanC(int* __restrict__ cursor,
                                               const int* __restrict__ boff) {
  const int i = blockIdx.x * 256 + threadIdx.x;
  if (i < NN) cursor[i] += boff[blockIdx.x];
}
// ----------------------------------------------------------------------------

__global__ __launch_bounds__(256) void k_fill(const int* __restrict__ row,
                                              const int* __restrict__ col,
                                              int* __restrict__ cursor,
                                              int* __restrict__ csr) {
  int e = blockIdx.x * 256 + threadIdx.x;
  if (e < NE) {
    int pos = atomicAdd(&cursor[row[e]], 1);
    csr[pos] = col[e];
  }
}

// Split W (fp32 [128][128]) into bf16 hi/lo arrays (RNE both stages).
__global__ __launch_bounds__(256) void k_wsplit(const float* __restrict__ W,
                                                ushort_t* __restrict__ Wh,
                                                ushort_t* __restrict__ Wl) {
  int i = blockIdx.x * 256 + threadIdx.x;        // 16384 elems, grid 64
  float w = W[i];
  unsigned fb = __float_as_uint(w);
  unsigned hb = (fb + 0x7fffu + ((fb >> 16) & 1u)) >> 16;
  float hf = __uint_as_float(hb << 16);
  float r = w - hf;
  unsigned rb = __float_as_uint(r);
  unsigned lb = (rb + 0x7fffu + ((rb >> 16) & 1u)) >> 16;
  Wh[i] = (ushort_t)hb;
  Wl[i] = (ushort_t)lb;
}

__device__ inline unsigned pack_split(float m) {
  unsigned fb = __float_as_uint(m);
  unsigned hb = (fb + 0x7fffu + ((fb >> 16) & 1u)) >> 16;   // RNE bf16
  float hf = __uint_as_float(hb << 16);
  float r = m - hf;
  unsigned rb = __float_as_uint(r);
  unsigned lb = (rb + 0x7fffu + ((rb >> 16) & 1u)) >> 16;   // RNE bf16 of residual
  return (hb << 16) | (lb & 0xffffu);
}

// One wave per destination node. Half-wave per edge, float4 row loads (each
// instruction covers 2 edges x 512B = 1KiB). 8 gathers in flight per half-wave.
// Writes the mean row PACKED as (bf16_hi<<16)|bf16_lo into d_out (same 4B/elem).
__global__ __launch_bounds__(256) void k_agg(const float4* __restrict__ x4,
                                             const int* __restrict__ csr,
                                             const int* __restrict__ deg,
                                             const int* __restrict__ cursor,
                                             uint4* __restrict__ outp) {
  const int wid  = threadIdx.x >> 6;
  const int lane = threadIdx.x & 63;
  const int half = lane >> 5;      // which edge of the pair
  const int fl   = lane & 31;      // float4 slot within the 128-float row
  const int n = blockIdx.x * 4 + wid;        // grid = 10000 -> exact
  const int end = cursor[n];                 // after k_fill: start + deg
  const int d = deg[n];
  const int start = end - d;
  float ax = 0.f, ay = 0.f, az = 0.f, aw = 0.f;
  for (int j = 0; j < d; j += 16) {
#pragma unroll
    for (int u = 0; u < 8; ++u) {
      int jj = j + 2 * u + half;
      if (jj < d) {
        int c = csr[start + jj];
        float4 v = x4[(size_t)c * 32 + fl];
        ax += v.x; ay += v.y; az += v.z; aw += v.w;
      }
    }
  }
  ax += __shfl_xor(ax, 32);
  ay += __shfl_xor(ay, 32);
  az += __shfl_xor(az, 32);
  aw += __shfl_xor(aw, 32);
  const float sc = 1.0f / ((float)d + EPS);
  if (half == 0) {
    uint4 o;
    o.x = pack_split(ax * sc);
    o.y = pack_split(ay * sc);
    o.z = pack_split(az * sc);
    o.w = pack_split(aw * sc);
    outp[(size_t)n * 32 + fl] = o;
  }
}

#define MFMA16(a, b, c) __builtin_amdgcn_mfma_f32_16x16x32_bf16((a), (b), (c), 0, 0, 0)

// In-place: d_out currently holds packed hi/lo mean rows; overwrite with fp32
// out = mean @ W^T + b via MFMA.  One wave per 16-row M-tile (2500 tiles, 625
// blocks). Fragment pattern (m91-verified B^T GEMM): lane l reads
// A[row = l&15][k = (l>>4)*8 + j] and B[f = ftile*16 + (l&15)][same k]; C/D:
// col = lane&15, row = (lane>>4)*4 + reg. 3 products: AhBh + AhBl + AlBh
// (AlBl ~1e-5, dropped). No LDS, no barriers; all A reads precede stores.
// packed/out alias intentionally -> NOT __restrict__.
__global__ __launch_bounds__(256) void k_gemm(const unsigned* packed,
                                              const ushort_t* __restrict__ Wh,
                                              const ushort_t* __restrict__ Wl,
                                              const float* __restrict__ bias,
                                              float* out) {
  const int wid  = threadIdx.x >> 6;
  const int lane = threadIdx.x & 63;
  const int mt = blockIdx.x * 4 + wid;       // M-tile; 625*4 = 2500 -> exact
  const int r  = lane & 15;
  const int kg = lane >> 4;                  // 0..3
  const int arow = mt * 16 + r;
  f32x4 acc[8];
#pragma unroll
  for (int t = 0; t < 8; ++t) acc[t] = (f32x4){0.f, 0.f, 0.f, 0.f};
#pragma unroll
  for (int s = 0; s < 4; ++s) {              // k-step: k = s*32 + kg*8 .. +7
    const unsigned* ap = packed + (size_t)arow * 128 + s * 32 + kg * 8;
    const uint4 u0 = *(const uint4*)ap;
    const uint4 u1 = *(const uint4*)(ap + 4);
    bf16x8 Ah, Al;
    Ah[0] = (short)(u0.x >> 16); Al[0] = (short)u0.x;
    Ah[1] = (short)(u0.y >> 16); Al[1] = (short)u0.y;
    Ah[2] = (short)(u0.z >> 16); Al[2] = (short)u0.z;
    Ah[3] = (short)(u0.w >> 16); Al[3] = (short)u0.w;
    Ah[4] = (short)(u1.x >> 16); Al[4] = (short)u1.x;
    Ah[5] = (short)(u1.y >> 16); Al[5] = (short)u1.y;
    Ah[6] = (short)(u1.z >> 16); Al[6] = (short)u1.z;
    Ah[7] = (short)(u1.w >> 16); Al[7] = (short)u1.w;
#pragma unroll
    for (int t = 0; t < 8; ++t) {
      const size_t wo = (size_t)(t * 16 + r) * 128 + s * 32 + kg * 8;
      const bf16x8 Bh = *(const bf16x8*)(Wh + wo);
      const bf16x8 Bl = *(const bf16x8*)(Wl + wo);
      acc[t] = MFMA16(Ah, Bh, acc[t]);
      acc[t] = MFMA16(Ah, Bl, acc[t]);
      acc[t] = MFMA16(Al, Bh, acc[t]);
    }
  }
#pragma unroll
  for (int t = 0; t < 8; ++t) {
    const int f = t * 16 + r;                // C/D col = lane&15
    const float bf = bias[f];
#pragma unroll
    for (int j = 0; j < 4; ++j) {            // C/D row = kg*4 + j
      const int orow = mt * 16 + kg * 4 + j;
      out[(size_t)orow * 128 + f] = acc[t][j] + bf;
    }
  }
}

extern "C" void kernel_launch(void* const* d_in, const int* in_sizes, int n_in,
                              void* d_out, int out_size, void* d_ws, size_t ws_size,
                              hipStream_t stream) {
  const float* x   = (const float*)d_in[0];
  const int*   row = (const int*)d_in[1];
  const int*   col = (const int*)d_in[2];
  const float* W   = (const float*)d_in[3];
  const float* b   = (const float*)d_in[4];
  float* out = (float*)d_out;

  char* ws = (char*)d_ws;
  int*      deg    = (int*)(ws + 0);         // 160000 B
  int*      cursor = (int*)(ws + 163840);    // 160000 B
  int*      csr    = (int*)(ws + 327680);    // 2560000 B
  ushort_t* Wh     = (ushort_t*)(ws + 2887680);  // 32768 B
  ushort_t* Wl     = (ushort_t*)(ws + 2920448);  // 32768 B
  int*      bsum   = (int*)(ws + 2953216);   // 628 B (padded 1024)
  int*      boff   = (int*)(ws + 2954240);   // 628 B -> total ~2.96 MB

  hipMemsetAsync(deg, 0, NN * sizeof(int), stream);
  k_wsplit<<<64,       256, 0, stream>>>(W, Wh, Wl);
  k_count <<<NE / 256, 256, 0, stream>>>(row, deg);
  k_scanA <<<NB,       256, 0, stream>>>(deg, cursor, bsum);
  k_scanB <<<1,        256, 0, stream>>>(bsum, boff);
  k_scanC <<<NB,       256, 0, stream>>>(cursor, boff);
  k_fill  <<<NE / 256, 256, 0, stream>>>(row, col, cursor, csr);
  k_agg   <<<NN / 4,   256, 0, stream>>>((const float4*)x, csr, deg, cursor,
                                         (uint4*)out);
  k_gemm  <<<NN / 64,  256, 0, stream>>>((const unsigned*)out, Wh, Wl, b, out);
}